// Round 4
// baseline (130.120 us; speedup 1.0000x reference)
//
#include <hip/hip_runtime.h>
#include <math.h>

// Problem constants (match reference)
#define NB   128   // batch
#define NN   16    // N agents
#define MM   32    // M other agents
#define DD   128   // obs dim = output dim = av dim
#define DOA  136   // obs+act dim
#define NACT 8
#define HH   64    // hidden
#define NTHR 512

// One workgroup per batch. Everything lives in LDS.
// Algebraic restructure:
//   av[b,j,k,:] = (j==k) ? av_pol[b,k,:] : av_act[b,k,:]
//   wav[b,i,j,:] = base[b,i,:] + weight[b,i,j]*diff[b,j,:]
//   value[b,i,j] = sum_h lrelu(U[b,i,h] + weight[b,i,j]*V[b,j,h]) * W2[h]
__launch_bounds__(NTHR, 1)
__global__ void critic_fused(
    const float* __restrict__ states,     // [B,N,128]
    const float* __restrict__ policies,   // [B,N,8]
    const float* __restrict__ actions,    // [B,N,8]
    const float* __restrict__ states_o,   // [B,M,128]
    const float* __restrict__ actions_o,  // [B,M,8]
    const float* __restrict__ Wk,         // [128,128] (in,out)
    const float* __restrict__ Wq,
    const float* __restrict__ Wv,         // [136,128]
    const float* __restrict__ Wk_o,
    const float* __restrict__ Wq_o,
    const float* __restrict__ Wv_o,       // [136,128]
    const float* __restrict__ W1,         // [256,64]
    const float* __restrict__ W2,         // [64,1]
    float* __restrict__ out)              // value[B*256] | weight[B*256] | weight_o[B*512]
{
    __shared__ float s_st[NN][DD];
    __shared__ float s_pol[NN][NACT];
    __shared__ float s_act[NN][NACT];
    __shared__ float s_sto[MM][DD];
    __shared__ float s_acto[MM][NACT];
    __shared__ float s_q[NN][DD];
    __shared__ float s_k[NN][DD];
    __shared__ float s_qo[NN][DD];
    __shared__ float s_avact[NN][DD];
    __shared__ float s_avpol[NN][DD];
    __shared__ float s_ko[MM][DD];
    __shared__ float s_avo[MM][DD];
    __shared__ float s_w[NN][NN];       // weight (softmaxed)
    __shared__ float s_wo[NN][MM];      // weight_o (softmaxed)
    __shared__ float s_base[NN][DD];
    __shared__ float s_wavo[NN][DD];
    __shared__ float s_U[NN][HH + 1];   // +1 pad: bank-conflict-free j-varying reads
    __shared__ float s_V[NN][HH + 1];
    __shared__ float s_W2[HH];

    const int t = threadIdx.x;
    const int b = blockIdx.x;

    // ---------------- load per-batch inputs ----------------
    {
        const float* p = states + b * NN * DD;
        for (int i = t; i < NN * DD; i += NTHR) (&s_st[0][0])[i] = p[i];
        const float* po = states_o + b * MM * DD;
        for (int i = t; i < MM * DD; i += NTHR) (&s_sto[0][0])[i] = po[i];
        if (t < NN * NACT) {
            (&s_pol[0][0])[t] = policies[b * NN * NACT + t];
            (&s_act[0][0])[t] = actions[b * NN * NACT + t];
        }
        if (t < MM * NACT) (&s_acto[0][0])[t] = actions_o[b * MM * NACT + t];
        if (t < HH) s_W2[t] = W2[t];
    }
    __syncthreads();

    const int c = t & (DD - 1);  // output column 0..127
    const int g = t >> 7;        // row group 0..3

    // ---------------- projections from states: q, k, q_o, av_act, av_pol ----------------
    {
        float aq[4] = {0,0,0,0}, ak[4] = {0,0,0,0}, aqo[4] = {0,0,0,0}, av[4] = {0,0,0,0};
        for (int kk = 0; kk < DD; ++kk) {
            float wq  = Wq  [kk * DD + c];
            float wk  = Wk  [kk * DD + c];
            float wqo = Wq_o[kk * DD + c];
            float wv  = Wv  [kk * DD + c];
            #pragma unroll
            for (int r = 0; r < 4; ++r) {
                float x = s_st[g + 4 * r][kk];
                aq[r]  += x * wq;
                ak[r]  += x * wk;
                aqo[r] += x * wqo;
                av[r]  += x * wv;   // common (k<128) part of both av_act and av_pol
            }
        }
        float aa[4], ap[4];
        #pragma unroll
        for (int r = 0; r < 4; ++r) { aa[r] = av[r]; ap[r] = av[r]; }
        for (int kk = 0; kk < NACT; ++kk) {
            float wv = Wv[(DD + kk) * DD + c];
            #pragma unroll
            for (int r = 0; r < 4; ++r) {
                aa[r] += s_act[g + 4 * r][kk] * wv;
                ap[r] += s_pol[g + 4 * r][kk] * wv;
            }
        }
        #pragma unroll
        for (int r = 0; r < 4; ++r) {
            int row = g + 4 * r;
            s_q [row][c] = aq[r];
            s_k [row][c] = ak[r];
            s_qo[row][c] = aqo[r];
            s_avact[row][c] = tanhf(aa[r]);
            s_avpol[row][c] = tanhf(ap[r]);
        }
    }

    // ---------------- projections from states_other: k_o, av_o ----------------
    {
        float ak[8] = {0,0,0,0,0,0,0,0}, av[8] = {0,0,0,0,0,0,0,0};
        for (int kk = 0; kk < DD; ++kk) {
            float wko = Wk_o[kk * DD + c];
            float wvo = Wv_o[kk * DD + c];
            #pragma unroll
            for (int r = 0; r < 8; ++r) {
                float x = s_sto[g + 4 * r][kk];
                ak[r] += x * wko;
                av[r] += x * wvo;
            }
        }
        for (int kk = 0; kk < NACT; ++kk) {
            float wvo = Wv_o[(DD + kk) * DD + c];
            #pragma unroll
            for (int r = 0; r < 8; ++r) av[r] += s_acto[g + 4 * r][kk] * wvo;
        }
        #pragma unroll
        for (int r = 0; r < 8; ++r) {
            int row = g + 4 * r;
            s_ko [row][c] = ak[r];
            s_avo[row][c] = tanhf(av[r]);
        }
    }
    __syncthreads();

    // ---------------- attention scores ----------------
    const float scale = 0.08838834764831845f;  // 1/sqrt(128)
    {
        int i = t >> 5, m = t & 31;  // 512 threads -> all 16x32 score_o entries
        float acc = 0.f;
        for (int d = 0; d < DD; ++d) acc += s_qo[i][d] * s_ko[m][d];
        s_wo[i][m] = acc * scale;
    }
    if (t < NN * NN) {
        int i = t >> 4, j = t & 15;
        float acc = 0.f;
        for (int d = 0; d < DD; ++d) acc += s_q[i][d] * s_k[j][d];
        s_w[i][j] = acc * scale;
    }
    __syncthreads();

    // ---------------- softmaxes ----------------
    if (t < NN) {
        // weight: softmax over j (last axis), row i = t
        int i = t;
        float mx = -1e30f;
        #pragma unroll
        for (int j = 0; j < NN; ++j) mx = fmaxf(mx, s_w[i][j]);
        float e[NN];
        float sum = 0.f;
        #pragma unroll
        for (int j = 0; j < NN; ++j) { e[j] = expf(s_w[i][j] - mx); sum += e[j]; }
        float inv = 1.f / sum;
        #pragma unroll
        for (int j = 0; j < NN; ++j) s_w[i][j] = e[j] * inv;
    } else if (t >= 64 && t < 64 + MM) {
        // weight_o: softmax over i (axis=1), column m
        int m = t - 64;
        float mx = -1e30f;
        #pragma unroll
        for (int i = 0; i < NN; ++i) mx = fmaxf(mx, s_wo[i][m]);
        float e[NN];
        float sum = 0.f;
        #pragma unroll
        for (int i = 0; i < NN; ++i) { e[i] = expf(s_wo[i][m] - mx); sum += e[i]; }
        float inv = 1.f / sum;
        #pragma unroll
        for (int i = 0; i < NN; ++i) s_wo[i][m] = e[i] * inv;
    }
    __syncthreads();

    // ---------------- write attention-weight outputs ----------------
    {
        float* ow  = out + NB * NN * NN;      // ret_weight [B,N,N]
        for (int i = t; i < NN * NN; i += NTHR) ow[b * NN * NN + i] = (&s_w[0][0])[i];
        float* owo = out + 2 * NB * NN * NN;  // weight_o   [B,N,M,1]
        for (int i = t; i < NN * MM; i += NTHR) owo[b * NN * MM + i] = (&s_wo[0][0])[i];
    }

    // ---------------- base = weight@av_act, wav_o = weight_o@av_o ----------------
    {
        #pragma unroll
        for (int r = 0; r < 4; ++r) {
            int i = g + 4 * r;
            float accb = 0.f, accw = 0.f;
            #pragma unroll
            for (int kk = 0; kk < NN; ++kk) accb += s_w[i][kk] * s_avact[kk][c];
            #pragma unroll
            for (int m = 0; m < MM; ++m) accw += s_wo[i][m] * s_avo[m][c];
            s_base[i][c] = accb;
            s_wavo[i][c] = accw;
        }
    }
    __syncthreads();

    // ---------------- U = base@W1a + wav_o@W1b, V = diff@W1a ----------------
    {
        int h = t & (HH - 1);
        int grp = t >> 6;           // 0..7
        int i0 = grp, i1 = grp + 8; // each thread: 2 U rows + 2 V rows (balanced waves)
        float u0 = 0.f, u1 = 0.f, v0 = 0.f, v1 = 0.f;
        for (int d = 0; d < DD; ++d) {
            float w1a = W1[d * HH + h];
            float w1b = W1[(DD + d) * HH + h];
            u0 += s_base[i0][d] * w1a;  u0 += s_wavo[i0][d] * w1b;
            u1 += s_base[i1][d] * w1a;  u1 += s_wavo[i1][d] * w1b;
            v0 += (s_avpol[i0][d] - s_avact[i0][d]) * w1a;
            v1 += (s_avpol[i1][d] - s_avact[i1][d]) * w1a;
        }
        s_U[i0][h] = u0; s_U[i1][h] = u1;
        s_V[i0][h] = v0; s_V[i1][h] = v1;
    }
    __syncthreads();

    // ---------------- value[i,j] = sum_h lrelu(U[i,h] + w[i,j]*V[j,h]) * W2[h] ----------------
    if (t < NN * NN) {
        int i = t >> 4, j = t & 15;
        float wij = s_w[i][j];
        float acc = 0.f;
        #pragma unroll
        for (int h = 0; h < HH; ++h) {
            float x = s_U[i][h] + wij * s_V[j][h];
            x = (x > 0.f) ? x : 0.01f * x;  // leaky_relu, slope 0.01
            acc += x * s_W2[h];
        }
        out[b * NN * NN + i * NN + j] = acc;
    }
}

extern "C" void kernel_launch(void* const* d_in, const int* in_sizes, int n_in,
                              void* d_out, int out_size, void* d_ws, size_t ws_size,
                              hipStream_t stream) {
    const float* states    = (const float*)d_in[0];
    const float* policies  = (const float*)d_in[1];
    const float* actions   = (const float*)d_in[2];
    const float* states_o  = (const float*)d_in[3];
    const float* actions_o = (const float*)d_in[4];
    const float* Wk        = (const float*)d_in[5];
    const float* Wq        = (const float*)d_in[6];
    const float* Wv        = (const float*)d_in[7];
    const float* Wk_o      = (const float*)d_in[8];
    const float* Wq_o      = (const float*)d_in[9];
    const float* Wv_o      = (const float*)d_in[10];
    const float* W1        = (const float*)d_in[11];
    const float* W2        = (const float*)d_in[12];
    float* out = (float*)d_out;

    hipLaunchKernelGGL(critic_fused, dim3(NB), dim3(NTHR), 0, stream,
                       states, policies, actions, states_o, actions_o,
                       Wk, Wq, Wv, Wk_o, Wq_o, Wv_o, W1, W2, out);
}